// Round 4
// baseline (290.065 us; speedup 1.0000x reference)
//
#include <hip/hip_runtime.h>
#include <math.h>

// Problem constants (from reference setup_inputs): B=16, A=16384, C=81, TOP_K=64
constexpr int B_N  = 16;
constexpr int A_N  = 16384;
constexpr int C_N  = 81;
constexpr int TOPK = 64;
constexpr int DNT  = 256;            // decode kernel block size
constexpr int NBINS = 232;           // score-bit bins covering (0.3, 1.0)
constexpr int CAP   = 512;           // candidate band capacity (pow2, 8/lane)
constexpr unsigned BIN_BASE = 0x3E99u;   // __float_as_uint(0.3f) >> 16
constexpr int SNT = 256;             // streaming select block size
constexpr int BC_N = B_N * C_N;      // 1296

// sigmoid+transpose tile: 64 anchors x 81 classes, linear LDS (round-1 v4).
constexpr int TA   = 64;
constexpr int TNT  = 256;
constexpr int TILE_ELEMS = TA * C_N;       // 5184
constexpr int TILE_F4    = TILE_ELEMS / 4; // 1296

// ---------------------------------------------------------------------------
// Kernel 1: SSD box decode (unchanged — bit-exact vs ref across all rounds).
// ---------------------------------------------------------------------------
__global__ __launch_bounds__(DNT) void decode_kernel(const float4* __restrict__ loc,
                                                     const float4* __restrict__ anch,
                                                     float4* __restrict__ boxes) {
    int i = blockIdx.x * DNT + threadIdx.x;
    int a = i & (A_N - 1);
    float4 l  = loc[i];
    float4 an = anch[a];
    float cx = an.x + (l.x * 0.1f) * an.z;
    float cy = an.y + (l.y * 0.1f) * an.w;
    float w  = an.z * expf(l.z * 0.2f);
    float h  = an.w * expf(l.w * 0.2f);
    float x1 = cx - w * 0.5f;
    float y1 = cy - h * 0.5f;
    boxes[i] = make_float4(x1, y1, x1 + w, y1 + h);
}

// ---------------------------------------------------------------------------
// Kernel 1b: fused sigmoid + transpose (round-1 v4, passed).
// ---------------------------------------------------------------------------
__global__ __launch_bounds__(TNT) void sigT_kernel(const float* __restrict__ conf,
                                                   float* __restrict__ scoresT) {
    __shared__ float4 tile4[TILE_F4];          // 20.7 KB, linear (mirrors global)
    float* tile = (float*)tile4;

    const int a0 = blockIdx.x * TA;
    const int b  = blockIdx.y;
    const int t  = threadIdx.x;

    const float4* src = (const float4*)(conf + ((size_t)b * A_N + a0) * C_N);
#pragma unroll
    for (int i = 0; i < (TILE_F4 + TNT - 1) / TNT; ++i) {   // 6 iters (last partial)
        int idx4 = i * TNT + t;
        if (idx4 < TILE_F4) {
            float4 x = src[idx4];                            // dwordx4, coalesced
            float4 v;
            v.x = 1.0f / (1.0f + expf(-x.x));
            v.y = 1.0f / (1.0f + expf(-x.y));
            v.z = 1.0f / (1.0f + expf(-x.z));
            v.w = 1.0f / (1.0f + expf(-x.w));
            tile4[idx4] = v;                                 // ds_write_b128, dense
        }
    }
    __syncthreads();
    float* dst = scoresT + (size_t)b * C_N * A_N + a0;
#pragma unroll
    for (int i = 0; i < (TILE_F4 + TNT - 1) / TNT; ++i) {
        int idx4 = i * TNT + t;
        if (idx4 < TILE_F4) {
            int cc  = idx4 >> 4;                   // 16 float4 per class row
            int al4 = idx4 & 15;
            int e   = al4 * 4 * C_N + cc;
            float4 v;
            v.x = tile[e];
            v.y = tile[e + C_N];
            v.z = tile[e + 2 * C_N];
            v.w = tile[e + 3 * C_N];
            ((float4*)(dst + (size_t)cc * A_N))[al4] = v;   // dwordx4 stores
        }
    }
}

// ---------------------------------------------------------------------------
// OLD scan routine (kept verbatim for tier-2/tier-3 fallback paths).
// ---------------------------------------------------------------------------
__device__ __forceinline__ void sort_gather_scan64(
        unsigned long long* cand, float4* cbox, int C, int lane,
        const float4* __restrict__ bptr, float* __restrict__ optr,
        float& rx1, float& ry1, float& rx2, float& ry2, float& rar,
        int& acc, int& kout) {
    unsigned long long key[8];
#pragma unroll
    for (int r = 0; r < 8; ++r) {
        int sidx = r * 64 + lane;
        key[r] = (sidx < C) ? cand[sidx] : 0ull;   // pad: 0 < any real key
    }
#pragma unroll
    for (int k = 2; k <= CAP; k <<= 1) {
#pragma unroll
        for (int j = k >> 1; j > 0; j >>= 1) {
            if (j >= 64) {
                int jr = j >> 6;               // 1,2,4: in-lane pairs
#pragma unroll
                for (int r = 0; r < 8; ++r) {
                    int rp = r ^ jr;
                    if (rp > r) {
                        int e = r * 64 + lane;
                        bool up = ((e & k) == 0);
                        unsigned long long va = key[r], vb = key[rp];
                        bool sw = up ? (va < vb) : (va > vb);
                        if (sw) { key[r] = vb; key[rp] = va; }
                    }
                }
            } else {                            // cross-lane via shfl
#pragma unroll
                for (int r = 0; r < 8; ++r) {
                    int e = r * 64 + lane;
                    bool up    = ((e & k) == 0);
                    bool isLow = ((lane & j) == 0);
                    unsigned long long va = key[r];
                    unsigned long long vb = __shfl_xor(va, j, 64);
                    bool keepMax = (up == isLow);
                    key[r] = keepMax ? (va > vb ? va : vb) : (va < vb ? va : vb);
                }
            }
        }
    }
    __syncthreads();
#pragma unroll
    for (int r = 0; r < 8; ++r) cand[r * 64 + lane] = key[r];
    __syncthreads();
#pragma unroll
    for (int r = 0; r < 8; ++r) {
        int e = r * 64 + lane;
        if (e < C) cbox[e] = bptr[(int)(~(unsigned)cand[e])];
    }
    __syncthreads();

    int ts = 0;
    unsigned long long k0 = cand[0];
    float4 cb = cbox[0];
    while (ts < C) {
        unsigned long long nk = 0ull;
        float4 nb = cb;
        if (ts + 1 < C) { nk = cand[ts + 1]; nb = cbox[ts + 1]; }
        float sc = __uint_as_float((unsigned)(k0 >> 32));
        float ca = (cb.z - cb.x) * (cb.w - cb.y);
        bool over = false;
        if (lane < acc) {
            float tlx = fmaxf(rx1, cb.x);
            float tly = fmaxf(ry1, cb.y);
            float brx = fminf(rx2, cb.z);
            float bry = fminf(ry2, cb.w);
            float iw  = fmaxf(brx - tlx, 0.0f);
            float ih  = fmaxf(bry - tly, 0.0f);
            float inter = iw * ih;
            float iou = inter / (rar + ca - inter);   // ref operand order
            over = iou > 0.5f;
        }
        if (!__any(over)) {
            if (lane == acc) { rx1 = cb.x; ry1 = cb.y; rx2 = cb.z; ry2 = cb.w; rar = ca; }
            if (lane == 0) {
                float* o = optr + (size_t)kout * 5;
                o[0] = sc; o[1] = cb.x; o[2] = cb.y; o[3] = cb.z; o[4] = cb.w;
            }
            acc++; kout++;
            if (acc == TOPK) break;
        }
        ++ts; k0 = nk; cb = nb;
    }
}

// ---------------------------------------------------------------------------
// NEW: sortless argmax NMS. Greedy NMS = repeatedly take highest-score alive
// candidate (exactly the reference: argmax + suppress). Keys are unique
// ((score_bits<<32)|~idx), so repeated argmax == sorted-scan-with-mask ==
// all previously passing rounds, pair-for-pair: every candidate is compared
// against every earlier-accepted box with the same fmax/fmin/div expressions
// and operand order. Dead candidates are key==0 (real keys always nonzero:
// score bits >= 0x3E99xxxx). Winner self-suppresses via IoU==1 (areas are
// strictly positive: w,h from exp() — proven on this data in round 3).
// ---------------------------------------------------------------------------
__device__ __forceinline__ void suppress_keys(
        unsigned long long (&key)[8],
        const float4 (&breg)[8], const float (&careg)[8],
        const float4& bb, float bar) {
#pragma unroll
    for (int r = 0; r < 8; ++r) {
        float tlx = fmaxf(bb.x, breg[r].x);          // fmax(accepted, candidate)
        float tly = fmaxf(bb.y, breg[r].y);
        float brx = fminf(bb.z, breg[r].z);
        float bry = fminf(bb.w, breg[r].w);
        float iw  = fmaxf(brx - tlx, 0.0f);
        float ih  = fmaxf(bry - tly, 0.0f);
        float inter = iw * ih;
        float iou = inter / (bar + careg[r] - inter); // (accepted_area + cand_area - inter)
        if (iou > 0.5f) key[r] = 0ull;
    }
}

__device__ __forceinline__ void process_band_argmax(
        unsigned long long (&key)[8], int C, int lane,
        const float4* __restrict__ bptr, float* __restrict__ optr,
        float4* abox, float* aar, int& acc, int& kout) {
    // ---- gather candidate boxes + areas into registers (8 scattered loads) ----
    float4 breg[8];
    float  careg[8];
#pragma unroll
    for (int r = 0; r < 8; ++r) {
        int e = r * 64 + lane;
        float4 v = make_float4(0.f, 0.f, 0.f, 0.f);
        if (e < C) v = bptr[(int)(~(unsigned)key[r])];
        else       key[r] = 0ull;                  // pad slots dead
        breg[r]  = v;
        careg[r] = (v.z - v.x) * (v.w - v.y);      // same area expression
    }

    // ---- cross-band pre-suppression vs all previously accepted boxes ----
    for (int a = 0; a < acc; ++a) {
        float4 bb = abox[a];
        float  ba = aar[a];
        suppress_keys(key, breg, careg, bb, ba);
    }

    // ---- accept loop: serial depth = number of accepts ----
    while (acc < TOPK) {
        // local argmax over 8 register keys (static indexing only)
        unsigned long long bk = 0ull;
#pragma unroll
        for (int r = 0; r < 8; ++r)
            if (key[r] > bk) bk = key[r];
        // wave argmax: 6-step butterfly max on the 64-bit key
        unsigned long long gk = bk;
#pragma unroll
        for (int j = 1; j < 64; j <<= 1) {
            unsigned long long o = __shfl_xor(gk, j, 64);
            if (o > gk) gk = o;
        }
        if (gk == 0ull) break;                     // band exhausted

        // winner box via uniform (SGPR) load — key carries the anchor index
        unsigned hi  = (unsigned)(gk >> 32);
        int aidx = (int)__builtin_amdgcn_readfirstlane((int)(~(unsigned)gk));
        float4 wb = bptr[aidx];                    // scalar load, L2-hot
        float war = (wb.z - wb.x) * (wb.w - wb.y);

        if (lane == 0) {
            float* o = optr + (size_t)kout * 5;
            o[0] = __uint_as_float(hi);
            o[1] = wb.x; o[2] = wb.y; o[3] = wb.z; o[4] = wb.w;
            abox[acc] = wb; aar[acc] = war;
        }
        acc++; kout++;

        // suppress (winner clears its own slot: IoU with itself == 1 > 0.5)
        suppress_keys(key, breg, careg, wb, war);
    }
}

// ---------------------------------------------------------------------------
// Kernel 2a: STREAMING SELECT (unchanged from round 2 — proven).
// ---------------------------------------------------------------------------
__global__ __launch_bounds__(SNT) void select_kernel(
        const float* __restrict__ scoresT,
        unsigned long long* __restrict__ g_cand,
        int* __restrict__ g_hist,
        int* __restrict__ g_cnt,
        int* __restrict__ g_blo) {
    __shared__ int hist[NBINS];
    __shared__ int s_cnt;

    const int bc = blockIdx.x;             // b*C_N + c
    const int t  = threadIdx.x;

    for (int i = t; i < NBINS; i += SNT) hist[i] = 0;
    if (t == 0) s_cnt = 0;
    __syncthreads();

    const float4* sptr = (const float4*)(scoresT + (size_t)bc * A_N);

    // --- pass 1: histogram (coalesced float4 reads) ---
    for (int i = 0; i < A_N / 4 / SNT; ++i) {      // 16 iterations
        float4 s4 = sptr[t + SNT * i];
        float s[4] = {s4.x, s4.y, s4.z, s4.w};
#pragma unroll
        for (int q = 0; q < 4; ++q) {
            if (s[q] > 0.3f) {
                unsigned u = __float_as_uint(s[q]);
                int bin = (int)(u >> 16) - (int)BIN_BASE;
                bin = bin < 0 ? 0 : (bin > NBINS - 1 ? NBINS - 1 : bin);
                atomicAdd(&hist[bin], 1);
            }
        }
    }
    __syncthreads();

    // publish hist for kernel B's (rare) refill path
    for (int i = t; i < NBINS; i += SNT) g_hist[bc * NBINS + i] = hist[i];

    // --- band walk for band 0 (redundant on all threads, wave-uniform) ---
    int lo = NBINS, tot = 0;
    while (lo > 0) {
        int cnt = hist[lo - 1];
        if (tot + cnt > CAP) {
            if (tot == 0) { lo--; }                // single bin > CAP: take it (clamped)
            break;
        }
        tot += cnt; lo--;
    }
    const int bin_lo = lo;

    // --- pass 2: compact band 0 straight to workspace (L2-warm reads) ---
    if (bin_lo < NBINS) {
        for (int i = 0; i < A_N / 4 / SNT; ++i) {
            float4 s4 = sptr[t + SNT * i];
            float s[4] = {s4.x, s4.y, s4.z, s4.w};
#pragma unroll
            for (int q = 0; q < 4; ++q) {
                if (s[q] > 0.3f) {
                    unsigned u = __float_as_uint(s[q]);
                    int bin = (int)(u >> 16) - (int)BIN_BASE;
                    bin = bin < 0 ? 0 : (bin > NBINS - 1 ? NBINS - 1 : bin);
                    if (bin >= bin_lo && bin < NBINS) {
                        int slot = atomicAdd(&s_cnt, 1);
                        if (slot < CAP) {
                            unsigned a = (unsigned)(4 * (t + SNT * i) + q);
                            g_cand[(size_t)bc * CAP + slot] =
                                ((unsigned long long)u << 32) | (unsigned)(~a);
                        }
                    }
                }
            }
        }
    }
    __syncthreads();
    if (t == 0) {
        int C = s_cnt; if (C > CAP) C = CAP;
        g_cnt[bc] = C;
        g_blo[bc] = bin_lo;
    }
}

// ---------------------------------------------------------------------------
// Kernel 2b: SORTLESS ARGMAX NMS. One 64-thread wave per (b,c); ~6.3 KB LDS;
// all 1296 blocks resident from t=0. Band 0 keys load straight to registers;
// refill (rare) compacts via LDS then processes identically.
// ---------------------------------------------------------------------------
__global__ __launch_bounds__(64, 2) void nms_argmax_kernel(
        const float* __restrict__ scoresT,
        const float4* __restrict__ boxes,
        const unsigned long long* __restrict__ g_cand,
        const int* __restrict__ g_hist,
        const int* __restrict__ g_cnt,
        const int* __restrict__ g_blo,
        float* __restrict__ out) {
    __shared__ int hist[NBINS];
    __shared__ unsigned long long cand[CAP];       // refill compaction only
    __shared__ float4 abox[TOPK];
    __shared__ float  aar[TOPK];
    __shared__ int s_cnt;

    const int bc   = blockIdx.x;
    const int b    = bc / C_N;
    const int lane = threadIdx.x;

    const float4* sptr = (const float4*)(scoresT + (size_t)bc * A_N);
    const float4* bptr = boxes + (size_t)b * A_N;
    float* optr = out + (size_t)bc * TOPK * 5;

    for (int i = lane; i < NBINS; i += 64) hist[i] = g_hist[bc * NBINS + i];
    const int C0 = g_cnt[bc];
    int bin_hi   = g_blo[bc];              // band 0 consumed bins [bin_hi, NBINS)

    int acc = 0, kout = 0;

    if (C0 > 0) {
        unsigned long long key[8];
#pragma unroll
        for (int r = 0; r < 8; ++r) {
            int e = r * 64 + lane;
            key[r] = (e < C0) ? g_cand[(size_t)bc * CAP + e] : 0ull;  // coalesced
        }
        process_band_argmax(key, C0, lane, bptr, optr, abox, aar, acc, kout);
    }

    // --- refill loop (rare path; band walk + streaming compaction verbatim) ---
    while (acc < TOPK) {
        int lo = bin_hi, tot = 0;
        while (lo > 0) {
            int cnt = hist[lo - 1];
            if (tot + cnt > CAP) {
                if (tot == 0) { lo--; }
                break;
            }
            tot += cnt; lo--;
        }
        const int bin_lo = lo;
        if (bin_lo == bin_hi) break;               // exhausted
        if (lane == 0) s_cnt = 0;
        __syncthreads();

        for (int i = 0; i < A_N / 4 / 64; ++i) {
            float4 s4 = sptr[lane + 64 * i];
            float s[4] = {s4.x, s4.y, s4.z, s4.w};
#pragma unroll
            for (int q = 0; q < 4; ++q) {
                if (s[q] > 0.3f) {
                    unsigned u = __float_as_uint(s[q]);
                    int bin = (int)(u >> 16) - (int)BIN_BASE;
                    bin = bin < 0 ? 0 : (bin > NBINS - 1 ? NBINS - 1 : bin);
                    if (bin >= bin_lo && bin < bin_hi) {
                        int slot = atomicAdd(&s_cnt, 1);
                        if (slot < CAP) {
                            unsigned a = (unsigned)(4 * (lane + 64 * i) + q);
                            cand[slot] = ((unsigned long long)u << 32) | (unsigned)(~a);
                        }
                    }
                }
            }
        }
        __syncthreads();
        int C = s_cnt; if (C > CAP) C = CAP;
        if (C > 0) {
            unsigned long long key[8];
#pragma unroll
            for (int r = 0; r < 8; ++r) {
                int e = r * 64 + lane;
                key[r] = (e < C) ? cand[e] : 0ull;
            }
            process_band_argmax(key, C, lane, bptr, optr, abox, aar, acc, kout);
        }
        bin_hi = bin_lo;
    }

    // Zero-fill remaining rows (harness poisons d_out with 0xAA every launch).
    {
        float* o  = optr + (size_t)kout * 5;
        int   rem = (TOPK - kout) * 5;
        for (int i = lane; i < rem; i += 64) o[i] = 0.0f;
    }
}

// ---------------------------------------------------------------------------
// Tier-2: round-0 fused select+NMS (proven 80 µs) if ws lacks split buffers.
// ---------------------------------------------------------------------------
__global__ __launch_bounds__(SNT, 4) void select_nms_fused(
        const float* __restrict__ scoresT,
        const float4* __restrict__ boxes,
        float* __restrict__ out) {
    __shared__ int hist[NBINS];
    __shared__ unsigned long long cand[CAP];
    __shared__ float4 cbox[CAP];
    __shared__ int s_cnt, s_acc, s_kout;

    const int bc   = blockIdx.x;
    const int b    = bc / C_N;
    const int t    = threadIdx.x;
    const int lane = t & 63;
    const int wv   = t >> 6;

    for (int i = t; i < NBINS; i += SNT) hist[i] = 0;
    if (t == 0) { s_acc = 0; s_kout = 0; }
    __syncthreads();

    const float4* sptr = (const float4*)(scoresT + (size_t)bc * A_N);
    const float4* bptr = boxes + (size_t)b * A_N;
    float* optr = out + (size_t)bc * TOPK * 5;

    for (int i = 0; i < A_N / 4 / SNT; ++i) {
        float4 s4 = sptr[t + SNT * i];
        float s[4] = {s4.x, s4.y, s4.z, s4.w};
#pragma unroll
        for (int q = 0; q < 4; ++q) {
            if (s[q] > 0.3f) {
                unsigned u = __float_as_uint(s[q]);
                int bin = (int)(u >> 16) - (int)BIN_BASE;
                bin = bin < 0 ? 0 : (bin > NBINS - 1 ? NBINS - 1 : bin);
                atomicAdd(&hist[bin], 1);
            }
        }
    }
    __syncthreads();

    float rx1 = 0.f, ry1 = 0.f, rx2 = 0.f, ry2 = 0.f, rar = 0.f;
    int acc = 0, kout = 0;

    int bin_hi = NBINS;
    for (;;) {
        int lo = bin_hi, tot = 0;
        while (lo > 0) {
            int cnt = hist[lo - 1];
            if (tot + cnt > CAP) { if (tot == 0) { lo--; } break; }
            tot += cnt; lo--;
        }
        const int bin_lo = lo;
        if (bin_lo == bin_hi) break;
        if (t == 0) s_cnt = 0;
        __syncthreads();

        for (int i = 0; i < A_N / 4 / SNT; ++i) {
            float4 s4 = sptr[t + SNT * i];
            float s[4] = {s4.x, s4.y, s4.z, s4.w};
#pragma unroll
            for (int q = 0; q < 4; ++q) {
                if (s[q] > 0.3f) {
                    unsigned u = __float_as_uint(s[q]);
                    int bin = (int)(u >> 16) - (int)BIN_BASE;
                    bin = bin < 0 ? 0 : (bin > NBINS - 1 ? NBINS - 1 : bin);
                    if (bin >= bin_lo && bin < bin_hi) {
                        int slot = atomicAdd(&s_cnt, 1);
                        if (slot < CAP) {
                            unsigned a = (unsigned)(4 * (t + SNT * i) + q);
                            cand[slot] = ((unsigned long long)u << 32) | (unsigned)(~a);
                        }
                    }
                }
            }
        }
        __syncthreads();
        int C = s_cnt; if (C > CAP) C = CAP;

        if (C > 0) {
            if (wv == 0) {
                unsigned long long key[8];
#pragma unroll
                for (int r = 0; r < 8; ++r) {
                    int sidx = r * 64 + lane;
                    key[r] = (sidx < C) ? cand[sidx] : 0ull;
                }
#pragma unroll
                for (int k = 2; k <= CAP; k <<= 1) {
#pragma unroll
                    for (int j = k >> 1; j > 0; j >>= 1) {
                        if (j >= 64) {
                            int jr = j >> 6;
#pragma unroll
                            for (int r = 0; r < 8; ++r) {
                                int rp = r ^ jr;
                                if (rp > r) {
                                    int e = r * 64 + lane;
                                    bool up = ((e & k) == 0);
                                    unsigned long long va = key[r], vb = key[rp];
                                    bool sw = up ? (va < vb) : (va > vb);
                                    if (sw) { key[r] = vb; key[rp] = va; }
                                }
                            }
                        } else {
#pragma unroll
                            for (int r = 0; r < 8; ++r) {
                                int e = r * 64 + lane;
                                bool up    = ((e & k) == 0);
                                bool isLow = ((lane & j) == 0);
                                unsigned long long va = key[r];
                                unsigned long long vb = __shfl_xor(va, j, 64);
                                bool keepMax = (up == isLow);
                                key[r] = keepMax ? (va > vb ? va : vb)
                                                 : (va < vb ? va : vb);
                            }
                        }
                    }
                }
#pragma unroll
                for (int r = 0; r < 8; ++r) cand[r * 64 + lane] = key[r];
            }
            __syncthreads();

            for (int e = t; e < CAP; e += SNT)
                if (e < C) cbox[e] = bptr[(int)(~(unsigned)cand[e])];
            __syncthreads();

            if (wv == 0) {
                int ts = 0;
                unsigned long long k0 = cand[0];
                float4 cb = cbox[0];
                while (ts < C) {
                    unsigned long long nk = 0ull;
                    float4 nb = cb;
                    if (ts + 1 < C) { nk = cand[ts + 1]; nb = cbox[ts + 1]; }
                    float sc = __uint_as_float((unsigned)(k0 >> 32));
                    float ca = (cb.z - cb.x) * (cb.w - cb.y);
                    bool over = false;
                    if (lane < acc) {
                        float tlx = fmaxf(rx1, cb.x);
                        float tly = fmaxf(ry1, cb.y);
                        float brx = fminf(rx2, cb.z);
                        float bry = fminf(ry2, cb.w);
                        float iw  = fmaxf(brx - tlx, 0.0f);
                        float ih  = fmaxf(bry - tly, 0.0f);
                        float inter = iw * ih;
                        float iou = inter / (rar + ca - inter);
                        over = iou > 0.5f;
                    }
                    if (!__any(over)) {
                        if (lane == acc) { rx1 = cb.x; ry1 = cb.y; rx2 = cb.z; ry2 = cb.w; rar = ca; }
                        if (lane == 0) {
                            float* o = optr + (size_t)kout * 5;
                            o[0] = sc; o[1] = cb.x; o[2] = cb.y; o[3] = cb.z; o[4] = cb.w;
                        }
                        acc++; kout++;
                        if (acc == TOPK) break;
                    }
                    ++ts; k0 = nk; cb = nb;
                }
                if (lane == 0) { s_acc = acc; s_kout = kout; }
            }
            __syncthreads();
            if (s_acc >= TOPK) break;
        }
        bin_hi = bin_lo;
    }

    {
        const int ko = s_kout;
        float* o  = optr + (size_t)ko * 5;
        int   rem = (TOPK - ko) * 5;
        for (int i = t; i < rem; i += SNT) o[i] = 0.0f;
    }
}

// ---------------------------------------------------------------------------
// Tier-3 fallback: standalone one-wave NMS reading strided conf (r6-8 path).
// ---------------------------------------------------------------------------
__global__ __launch_bounds__(64, 4) void nms_fallback(const float* __restrict__ conf,
                                                      const float4* __restrict__ boxes,
                                                      float* __restrict__ out) {
    __shared__ int hist[NBINS];
    __shared__ unsigned long long cand[CAP];
    __shared__ float4 cbox[CAP];
    __shared__ int s_cnt;

    const int c    = blockIdx.x;
    const int b    = blockIdx.y;
    const int lane = threadIdx.x;

    const float4* bptr = boxes + (size_t)b * A_N;
    const float*  cptr = conf + (size_t)b * A_N * C_N + c;
    float* optr = out + (size_t)(b * C_N + c) * TOPK * 5;

    for (int i = lane; i < NBINS; i += 64) hist[i] = 0;
    __syncthreads();
    for (int i = 0; i < A_N / 256; ++i) {
        int a0 = 4 * (lane + 64 * i);
#pragma unroll
        for (int q = 0; q < 4; ++q) {
            float x = cptr[(size_t)(a0 + q) * C_N];
            float s = 1.0f / (1.0f + expf(-x));
            if (s > 0.3f) {
                unsigned u = __float_as_uint(s);
                int bin = (int)(u >> 16) - (int)BIN_BASE;
                bin = bin < 0 ? 0 : (bin > NBINS - 1 ? NBINS - 1 : bin);
                atomicAdd(&hist[bin], 1);
            }
        }
    }
    __syncthreads();

    float rx1 = 0.f, ry1 = 0.f, rx2 = 0.f, ry2 = 0.f, rar = 0.f;
    int acc = 0, kout = 0;
    int bin_hi = NBINS;
    for (;;) {
        int lo = bin_hi, tot = 0;
        while (lo > 0) {
            int cnt = hist[lo - 1];
            if (tot + cnt > CAP) { if (tot == 0) { lo--; } break; }
            tot += cnt; lo--;
        }
        const int bin_lo = lo;
        if (bin_lo == bin_hi) break;
        if (lane == 0) s_cnt = 0;
        __syncthreads();
        for (int i = 0; i < A_N / 256; ++i) {
            int a0 = 4 * (lane + 64 * i);
#pragma unroll
            for (int q = 0; q < 4; ++q) {
                float x = cptr[(size_t)(a0 + q) * C_N];
                float s = 1.0f / (1.0f + expf(-x));
                if (s > 0.3f) {
                    unsigned u = __float_as_uint(s);
                    int bin = (int)(u >> 16) - (int)BIN_BASE;
                    bin = bin < 0 ? 0 : (bin > NBINS - 1 ? NBINS - 1 : bin);
                    if (bin >= bin_lo && bin < bin_hi) {
                        int slot = atomicAdd(&s_cnt, 1);
                        if (slot < CAP)
                            cand[slot] = ((unsigned long long)u << 32) | (unsigned)(~(unsigned)(a0 + q));
                    }
                }
            }
        }
        __syncthreads();
        int C = s_cnt; if (C > CAP) C = CAP;
        if (C > 0)
            sort_gather_scan64(cand, cbox, C, lane, bptr, optr,
                               rx1, ry1, rx2, ry2, rar, acc, kout);
        if (acc == TOPK) break;
        bin_hi = bin_lo;
    }
    {
        float* o  = optr + (size_t)kout * 5;
        int   rem = (TOPK - kout) * 5;
        for (int i = lane; i < rem; i += 64) o[i] = 0.0f;
    }
}

extern "C" void kernel_launch(void* const* d_in, const int* in_sizes, int n_in,
                              void* d_out, int out_size, void* d_ws, size_t ws_size,
                              hipStream_t stream) {
    const float* loc     = (const float*)d_in[0];   // [B, A, 4]
    const float* conf    = (const float*)d_in[1];   // [B, A, C]
    const float* anchors = (const float*)d_in[2];   // [A, 4]
    float* out = (float*)d_out;                     // [B, C, TOPK, 5]

    const size_t boxes_bytes  = (size_t)B_N * A_N * sizeof(float4);          // 4 MB
    const size_t scores_bytes = (size_t)B_N * C_N * A_N * sizeof(float);     // 85 MB
    const size_t cand_bytes   = (size_t)BC_N * CAP * sizeof(unsigned long long); // 5.3 MB
    const size_t hist_bytes   = (size_t)BC_N * NBINS * sizeof(int);          // 1.2 MB
    const size_t cnt_bytes    = (size_t)BC_N * sizeof(int);
    const size_t full_bytes   = boxes_bytes + scores_bytes + cand_bytes +
                                hist_bytes + 2 * cnt_bytes;                  // ~95.7 MB

    float4* boxes = (float4*)d_ws;

    decode_kernel<<<(B_N * A_N) / DNT, DNT, 0, stream>>>(
        (const float4*)loc, (const float4*)anchors, boxes);

    if (ws_size >= full_bytes) {
        char* p = (char*)d_ws + boxes_bytes;
        float* scoresT = (float*)p;                 p += scores_bytes;
        unsigned long long* g_cand = (unsigned long long*)p; p += cand_bytes;
        int* g_hist = (int*)p;                      p += hist_bytes;
        int* g_cnt  = (int*)p;                      p += cnt_bytes;
        int* g_blo  = (int*)p;

        sigT_kernel<<<dim3(A_N / TA, B_N), TNT, 0, stream>>>(conf, scoresT);
        select_kernel<<<dim3(BC_N), SNT, 0, stream>>>(scoresT, g_cand, g_hist, g_cnt, g_blo);
        nms_argmax_kernel<<<dim3(BC_N), 64, 0, stream>>>(scoresT, boxes, g_cand,
                                                         g_hist, g_cnt, g_blo, out);
    } else if (ws_size >= boxes_bytes + scores_bytes) {
        float* scoresT = (float*)((char*)d_ws + boxes_bytes);
        sigT_kernel<<<dim3(A_N / TA, B_N), TNT, 0, stream>>>(conf, scoresT);
        select_nms_fused<<<dim3(BC_N), SNT, 0, stream>>>(scoresT, boxes, out);
    } else {
        nms_fallback<<<dim3(C_N, B_N), 64, 0, stream>>>(conf, boxes, out);
    }
}

// Round 5
// 268.315 us; speedup vs baseline: 1.0811x; 1.0811x over previous
//
#include <hip/hip_runtime.h>
#include <math.h>

// Problem constants (from reference setup_inputs): B=16, A=16384, C=81, TOP_K=64
constexpr int B_N  = 16;
constexpr int A_N  = 16384;
constexpr int C_N  = 81;
constexpr int TOPK = 64;
constexpr int DNT  = 256;            // decode kernel block size
constexpr int NBINS = 232;           // score-bit bins covering (0.3, 1.0)
constexpr int CAP   = 512;           // per-band capacity (pow2, 8/lane)
constexpr unsigned BIN_BASE = 0x3E99u;   // __float_as_uint(0.3f) >> 16
constexpr int SNT = 256;             // streaming select block size
constexpr int BC_N = B_N * C_N;      // 1296
constexpr int GCAP_MAX = 2048;       // max bucketed candidates per class

// Exact-compare constant: fl32(inter/den) > 0.5  <=>  inter > den*(0.5+2^-25)
// (24-bit x 25-bit mantissa product is exact in f64; RN rounding is monotone,
// tie at q=0.5+2^-25 rounds to even 0.5 -> strict > matches.)
#define IOU_HALF_EXACT 0x1.000001p-1

// sigmoid+transpose tile: 64 anchors x 81 classes, linear LDS (round-1 v4).
constexpr int TA   = 64;
constexpr int TNT  = 256;
constexpr int TILE_ELEMS = TA * C_N;       // 5184
constexpr int TILE_F4    = TILE_ELEMS / 4; // 1296

// ---------------------------------------------------------------------------
// Kernel 1: SSD box decode (unchanged — bit-exact vs ref across all rounds).
// ---------------------------------------------------------------------------
__global__ __launch_bounds__(DNT) void decode_kernel(const float4* __restrict__ loc,
                                                     const float4* __restrict__ anch,
                                                     float4* __restrict__ boxes) {
    int i = blockIdx.x * DNT + threadIdx.x;
    int a = i & (A_N - 1);
    float4 l  = loc[i];
    float4 an = anch[a];
    float cx = an.x + (l.x * 0.1f) * an.z;
    float cy = an.y + (l.y * 0.1f) * an.w;
    float w  = an.z * expf(l.z * 0.2f);
    float h  = an.w * expf(l.w * 0.2f);
    float x1 = cx - w * 0.5f;
    float y1 = cy - h * 0.5f;
    boxes[i] = make_float4(x1, y1, x1 + w, y1 + h);
}

// ---------------------------------------------------------------------------
// Kernel 1b: fused sigmoid + transpose (round-1 v4, passed).
// ---------------------------------------------------------------------------
__global__ __launch_bounds__(TNT) void sigT_kernel(const float* __restrict__ conf,
                                                   float* __restrict__ scoresT) {
    __shared__ float4 tile4[TILE_F4];          // 20.7 KB, linear (mirrors global)
    float* tile = (float*)tile4;

    const int a0 = blockIdx.x * TA;
    const int b  = blockIdx.y;
    const int t  = threadIdx.x;

    const float4* src = (const float4*)(conf + ((size_t)b * A_N + a0) * C_N);
#pragma unroll
    for (int i = 0; i < (TILE_F4 + TNT - 1) / TNT; ++i) {   // 6 iters (last partial)
        int idx4 = i * TNT + t;
        if (idx4 < TILE_F4) {
            float4 x = src[idx4];                            // dwordx4, coalesced
            float4 v;
            v.x = 1.0f / (1.0f + expf(-x.x));
            v.y = 1.0f / (1.0f + expf(-x.y));
            v.z = 1.0f / (1.0f + expf(-x.z));
            v.w = 1.0f / (1.0f + expf(-x.w));
            tile4[idx4] = v;                                 // ds_write_b128, dense
        }
    }
    __syncthreads();
    float* dst = scoresT + (size_t)b * C_N * A_N + a0;
#pragma unroll
    for (int i = 0; i < (TILE_F4 + TNT - 1) / TNT; ++i) {
        int idx4 = i * TNT + t;
        if (idx4 < TILE_F4) {
            int cc  = idx4 >> 4;                   // 16 float4 per class row
            int al4 = idx4 & 15;
            int e   = al4 * 4 * C_N + cc;
            float4 v;
            v.x = tile[e];
            v.y = tile[e + C_N];
            v.z = tile[e + 2 * C_N];
            v.w = tile[e + 3 * C_N];
            ((float4*)(dst + (size_t)cc * A_N))[al4] = v;   // dwordx4 stores
        }
    }
}

// ---------------------------------------------------------------------------
// OLD scan routine (kept verbatim for tier-2/tier-3 fallback paths).
// ---------------------------------------------------------------------------
__device__ __forceinline__ void sort_gather_scan64(
        unsigned long long* cand, float4* cbox, int C, int lane,
        const float4* __restrict__ bptr, float* __restrict__ optr,
        float& rx1, float& ry1, float& rx2, float& ry2, float& rar,
        int& acc, int& kout) {
    unsigned long long key[8];
#pragma unroll
    for (int r = 0; r < 8; ++r) {
        int sidx = r * 64 + lane;
        key[r] = (sidx < C) ? cand[sidx] : 0ull;   // pad: 0 < any real key
    }
#pragma unroll
    for (int k = 2; k <= CAP; k <<= 1) {
#pragma unroll
        for (int j = k >> 1; j > 0; j >>= 1) {
            if (j >= 64) {
                int jr = j >> 6;               // 1,2,4: in-lane pairs
#pragma unroll
                for (int r = 0; r < 8; ++r) {
                    int rp = r ^ jr;
                    if (rp > r) {
                        int e = r * 64 + lane;
                        bool up = ((e & k) == 0);
                        unsigned long long va = key[r], vb = key[rp];
                        bool sw = up ? (va < vb) : (va > vb);
                        if (sw) { key[r] = vb; key[rp] = va; }
                    }
                }
            } else {                            // cross-lane via shfl
#pragma unroll
                for (int r = 0; r < 8; ++r) {
                    int e = r * 64 + lane;
                    bool up    = ((e & k) == 0);
                    bool isLow = ((lane & j) == 0);
                    unsigned long long va = key[r];
                    unsigned long long vb = __shfl_xor(va, j, 64);
                    bool keepMax = (up == isLow);
                    key[r] = keepMax ? (va > vb ? va : vb) : (va < vb ? va : vb);
                }
            }
        }
    }
    __syncthreads();
#pragma unroll
    for (int r = 0; r < 8; ++r) cand[r * 64 + lane] = key[r];
    __syncthreads();
#pragma unroll
    for (int r = 0; r < 8; ++r) {
        int e = r * 64 + lane;
        if (e < C) cbox[e] = bptr[(int)(~(unsigned)cand[e])];
    }
    __syncthreads();

    int ts = 0;
    unsigned long long k0 = cand[0];
    float4 cb = cbox[0];
    while (ts < C) {
        unsigned long long nk = 0ull;
        float4 nb = cb;
        if (ts + 1 < C) { nk = cand[ts + 1]; nb = cbox[ts + 1]; }
        float sc = __uint_as_float((unsigned)(k0 >> 32));
        float ca = (cb.z - cb.x) * (cb.w - cb.y);
        bool over = false;
        if (lane < acc) {
            float tlx = fmaxf(rx1, cb.x);
            float tly = fmaxf(ry1, cb.y);
            float brx = fminf(rx2, cb.z);
            float bry = fminf(ry2, cb.w);
            float iw  = fmaxf(brx - tlx, 0.0f);
            float ih  = fmaxf(bry - tly, 0.0f);
            float inter = iw * ih;
            float iou = inter / (rar + ca - inter);   // ref operand order
            over = iou > 0.5f;
        }
        if (!__any(over)) {
            if (lane == acc) { rx1 = cb.x; ry1 = cb.y; rx2 = cb.z; ry2 = cb.w; rar = ca; }
            if (lane == 0) {
                float* o = optr + (size_t)kout * 5;
                o[0] = sc; o[1] = cb.x; o[2] = cb.y; o[3] = cb.z; o[4] = cb.w;
            }
            acc++; kout++;
            if (acc == TOPK) break;
        }
        ++ts; k0 = nk; cb = nb;
    }
}

// ---------------------------------------------------------------------------
// Suppress helper: mask-based, EXACT compare (no fp32 division sequence).
// fl32(inter/den) > 0.5  <=>  (f64)inter > (f64)den * (0.5+2^-25) — selection
// bit-identical to the division form used in all passing rounds.
// ---------------------------------------------------------------------------
__device__ __forceinline__ void suppress_mask(
        unsigned& aliveM, const float4& bb, float bar,
        const float4 (&breg)[8], const float (&careg)[8]) {
#pragma unroll
    for (int r = 0; r < 8; ++r) {
        float tlx = fmaxf(bb.x, breg[r].x);          // fmax(accepted, candidate)
        float tly = fmaxf(bb.y, breg[r].y);
        float brx = fminf(bb.z, breg[r].z);
        float bry = fminf(bb.w, breg[r].w);
        float iw  = fmaxf(brx - tlx, 0.0f);
        float ih  = fmaxf(bry - tly, 0.0f);
        float inter = iw * ih;
        float den = bar + careg[r] - inter;          // fl(fl(bar+ca)-inter), ref order
        if ((double)inter > (double)den * IOU_HALF_EXACT) aliveM &= ~(1u << r);
    }
}

// ---------------------------------------------------------------------------
// Band processor (r3 structure, proven fastest accepts): bitonic sort
// (verbatim network) + gather to regs/LDS + ballot-driven mask accept loop.
// Keys arrive in registers (from bucketed global or LDS-compacted rescan).
// ---------------------------------------------------------------------------
__device__ __forceinline__ void sort_mask_accept(
        unsigned long long (&key)[8], int C, int lane,
        unsigned long long* cand, float4* cbox, float4* abox, float* aar,
        const float4* __restrict__ bptr, float* __restrict__ optr,
        int& acc, int& kout) {
    // ---- wave bitonic sort (verbatim from passing rounds) ----
#pragma unroll
    for (int k = 2; k <= CAP; k <<= 1) {
#pragma unroll
        for (int j = k >> 1; j > 0; j >>= 1) {
            if (j >= 64) {
                int jr = j >> 6;               // 1,2,4: in-lane pairs
#pragma unroll
                for (int r = 0; r < 8; ++r) {
                    int rp = r ^ jr;
                    if (rp > r) {
                        int e = r * 64 + lane;
                        bool up = ((e & k) == 0);
                        unsigned long long va = key[r], vb = key[rp];
                        bool sw = up ? (va < vb) : (va > vb);
                        if (sw) { key[r] = vb; key[rp] = va; }
                    }
                }
            } else {                            // cross-lane via shfl
#pragma unroll
                for (int r = 0; r < 8; ++r) {
                    int e = r * 64 + lane;
                    bool up    = ((e & k) == 0);
                    bool isLow = ((lane & j) == 0);
                    unsigned long long va = key[r];
                    unsigned long long vb = __shfl_xor(va, j, 64);
                    bool keepMax = (up == isLow);
                    key[r] = keepMax ? (va > vb ? va : vb) : (va < vb ? va : vb);
                }
            }
        }
    }
    __syncthreads();
#pragma unroll
    for (int r = 0; r < 8; ++r) cand[r * 64 + lane] = key[r];   // for broadcasts
    __syncthreads();

    // ---- gather candidate boxes into registers (+LDS copy for broadcast) ----
    float4 breg[8];
    float  careg[8];
#pragma unroll
    for (int r = 0; r < 8; ++r) {
        int e = r * 64 + lane;
        float4 v = make_float4(0.f, 0.f, 0.f, 0.f);
        if (e < C) { v = bptr[(int)(~(unsigned)key[r])]; cbox[e] = v; }
        breg[r]  = v;
        careg[r] = (v.z - v.x) * (v.w - v.y);      // same area expression
    }
    __syncthreads();

    unsigned aliveM = 0;
#pragma unroll
    for (int r = 0; r < 8; ++r)
        if (r * 64 + lane < C) aliveM |= (1u << r);

    // ---- cross-band pre-suppression vs all previously accepted boxes ----
    for (int a = 0; a < acc; ++a)
        suppress_mask(aliveM, abox[a], aar[a], breg, careg);

    // ---- accept loop: ballot find-first on sorted order (cheapest accept) ----
    int rStart = 0;                               // first-alive index is monotone
    while (acc < TOPK) {
        int estar = -1;
        for (int r = rStart; r < 8; ++r) {
            unsigned long long m = __ballot((aliveM >> r) & 1);
            if (m != 0ull) { estar = r * 64 + __builtin_ctzll(m); rStart = r; break; }
        }
        if (estar < 0) break;                     // band exhausted

        unsigned long long k0 = cand[estar];      // uniform LDS broadcast
        float4 bb = cbox[estar];                  // uniform LDS broadcast
        float sc  = __uint_as_float((unsigned)(k0 >> 32));
        float bar = (bb.z - bb.x) * (bb.w - bb.y);

        if (lane == 0) {
            float* o = optr + (size_t)kout * 5;
            o[0] = sc; o[1] = bb.x; o[2] = bb.y; o[3] = bb.z; o[4] = bb.w;
            abox[acc] = bb; aar[acc] = bar;
        }
        acc++; kout++;

        suppress_mask(aliveM, bb, bar, breg, careg);  // clears own bit (IoU=1)
    }
}

// ---------------------------------------------------------------------------
// Kernel 2a: STREAMING SELECT v2 — hist + COUNTING-SORT scatter by bin.
// Candidates land in g_cand bucketed DESCENDING by bin (bin b at
// [sfx[b+1], sfx[b+1]+hist[b])), so any band (= consecutive whole bins) is a
// CONTIGUOUS slice. Only the first `gcap` positions are stored (guarded);
// NMS rescans scoresT for bands past gcap (rare). Hist/bins/keys verbatim.
// ---------------------------------------------------------------------------
__global__ __launch_bounds__(SNT) void select_kernel(
        const float* __restrict__ scoresT,
        unsigned long long* __restrict__ g_cand,
        int* __restrict__ g_hist,
        int gcap) {
    __shared__ int hist[NBINS];
    __shared__ int cur[NBINS];
    __shared__ int sfx[NBINS + 1];

    const int bc = blockIdx.x;             // b*C_N + c
    const int t  = threadIdx.x;

    for (int i = t; i < NBINS; i += SNT) { hist[i] = 0; cur[i] = 0; }
    __syncthreads();

    const float4* sptr = (const float4*)(scoresT + (size_t)bc * A_N);

    // --- pass 1: histogram (coalesced float4 reads) ---
    for (int i = 0; i < A_N / 4 / SNT; ++i) {      // 16 iterations
        float4 s4 = sptr[t + SNT * i];
        float s[4] = {s4.x, s4.y, s4.z, s4.w};
#pragma unroll
        for (int q = 0; q < 4; ++q) {
            if (s[q] > 0.3f) {
                unsigned u = __float_as_uint(s[q]);
                int bin = (int)(u >> 16) - (int)BIN_BASE;
                bin = bin < 0 ? 0 : (bin > NBINS - 1 ? NBINS - 1 : bin);
                atomicAdd(&hist[bin], 1);
            }
        }
    }
    __syncthreads();

    // publish hist; suffix sums (descending-bin storage bases)
    for (int i = t; i < NBINS; i += SNT) g_hist[bc * NBINS + i] = hist[i];
    if (t == 0) {
        sfx[NBINS] = 0;
        for (int b = NBINS - 1; b >= 0; --b) sfx[b] = sfx[b + 1] + hist[b];
    }
    __syncthreads();

    // --- pass 2: counting-sort scatter (only bins whose base fits gcap) ---
    unsigned long long* gc = g_cand + (size_t)bc * gcap;
    for (int i = 0; i < A_N / 4 / SNT; ++i) {
        float4 s4 = sptr[t + SNT * i];
        float s[4] = {s4.x, s4.y, s4.z, s4.w};
#pragma unroll
        for (int q = 0; q < 4; ++q) {
            if (s[q] > 0.3f) {
                unsigned u = __float_as_uint(s[q]);
                int bin = (int)(u >> 16) - (int)BIN_BASE;
                bin = bin < 0 ? 0 : (bin > NBINS - 1 ? NBINS - 1 : bin);
                int base = sfx[bin + 1];
                if (base < gcap) {
                    int g = base + atomicAdd(&cur[bin], 1);
                    if (g < gcap) {
                        unsigned a = (unsigned)(4 * (t + SNT * i) + q);
                        gc[g] = ((unsigned long long)u << 32) | (unsigned)(~a);
                    }
                }
            }
        }
    }
}

// ---------------------------------------------------------------------------
// Kernel 2b: BANDED NMS v5. One 64-thread wave per (b,c), all 1296 resident.
// Band walk identical to all passing rounds; bands within gcap load their
// candidates DIRECTLY from the bucketed array (no scoresT rescan, no
// arrival-order compaction); bands past gcap fall back to the verbatim
// rescan. Sort + ballot-accept per band (r3 structure, f64-exact IoU).
// ---------------------------------------------------------------------------
__global__ __launch_bounds__(64, 2) void nms_banded_kernel(
        const float* __restrict__ scoresT,
        const float4* __restrict__ boxes,
        const unsigned long long* __restrict__ g_cand,
        const int* __restrict__ g_hist,
        float* __restrict__ out,
        int gcap) {
    __shared__ int hist[NBINS];
    __shared__ int sfx[NBINS + 1];
    __shared__ unsigned long long cand[CAP];
    __shared__ float4 cbox[CAP];
    __shared__ float4 abox[TOPK];
    __shared__ float  aar[TOPK];
    __shared__ int s_cnt;

    const int bc   = blockIdx.x;
    const int b    = bc / C_N;
    const int lane = threadIdx.x;

    const float4* sptr = (const float4*)(scoresT + (size_t)bc * A_N);
    const float4* bptr = boxes + (size_t)b * A_N;
    const unsigned long long* gc = g_cand + (size_t)bc * gcap;
    float* optr = out + (size_t)bc * TOPK * 5;

    for (int i = lane; i < NBINS; i += 64) hist[i] = g_hist[bc * NBINS + i];
    __syncthreads();
    if (lane == 0) {
        sfx[NBINS] = 0;
        for (int bn = NBINS - 1; bn >= 0; --bn) sfx[bn] = sfx[bn + 1] + hist[bn];
    }
    __syncthreads();

    int acc = 0, kout = 0;
    int bin_hi = NBINS;

    while (acc < TOPK) {
        // --- band walk (verbatim semantics: tot<=CAP, single-bin clamp) ---
        int lo = bin_hi, tot = 0;
        while (lo > 0) {
            int cnt = hist[lo - 1];
            if (tot + cnt > CAP) {
                if (tot == 0) { lo--; }            // single bin > CAP: take it (clamped)
                break;
            }
            tot += cnt; lo--;
        }
        const int bin_lo = lo;
        if (bin_lo == bin_hi) break;               // all bins consumed -> exhausted

        const int start = sfx[bin_hi];
        int C = sfx[bin_lo] - start;
        if (C > CAP) C = CAP;                      // clamp case

        if (C > 0) {
            if (start + C <= gcap) {
                // --- direct load: band is a contiguous stored slice ---
                unsigned long long key[8];
#pragma unroll
                for (int r = 0; r < 8; ++r) {
                    int e = r * 64 + lane;
                    key[r] = (e < C) ? gc[start + e] : 0ull;   // coalesced
                }
                sort_mask_accept(key, C, lane, cand, cbox, abox, aar,
                                 bptr, optr, acc, kout);
            } else {
                // --- fallback: verbatim scoresT rescan + LDS compaction ---
                if (lane == 0) s_cnt = 0;
                __syncthreads();
                for (int i = 0; i < A_N / 4 / 64; ++i) {
                    float4 s4 = sptr[lane + 64 * i];
                    float s[4] = {s4.x, s4.y, s4.z, s4.w};
#pragma unroll
                    for (int q = 0; q < 4; ++q) {
                        if (s[q] > 0.3f) {
                            unsigned u = __float_as_uint(s[q]);
                            int bin = (int)(u >> 16) - (int)BIN_BASE;
                            bin = bin < 0 ? 0 : (bin > NBINS - 1 ? NBINS - 1 : bin);
                            if (bin >= bin_lo && bin < bin_hi) {
                                int slot = atomicAdd(&s_cnt, 1);
                                if (slot < CAP) {
                                    unsigned a = (unsigned)(4 * (lane + 64 * i) + q);
                                    cand[slot] = ((unsigned long long)u << 32) | (unsigned)(~a);
                                }
                            }
                        }
                    }
                }
                __syncthreads();
                int Cr = s_cnt; if (Cr > CAP) Cr = CAP;
                if (Cr > 0) {
                    unsigned long long key[8];
#pragma unroll
                    for (int r = 0; r < 8; ++r) {
                        int e = r * 64 + lane;
                        key[r] = (e < Cr) ? cand[e] : 0ull;
                    }
                    sort_mask_accept(key, Cr, lane, cand, cbox, abox, aar,
                                     bptr, optr, acc, kout);
                }
            }
        }
        bin_hi = bin_lo;
    }

    // Zero-fill remaining rows (harness poisons d_out with 0xAA every launch).
    {
        float* o  = optr + (size_t)kout * 5;
        int   rem = (TOPK - kout) * 5;
        for (int i = lane; i < rem; i += 64) o[i] = 0.0f;
    }
}

// ---------------------------------------------------------------------------
// Tier-2: round-0 fused select+NMS (proven 80 µs) if ws lacks split buffers.
// ---------------------------------------------------------------------------
__global__ __launch_bounds__(SNT, 4) void select_nms_fused(
        const float* __restrict__ scoresT,
        const float4* __restrict__ boxes,
        float* __restrict__ out) {
    __shared__ int hist[NBINS];
    __shared__ unsigned long long cand[CAP];
    __shared__ float4 cbox[CAP];
    __shared__ int s_cnt, s_acc, s_kout;

    const int bc   = blockIdx.x;
    const int b    = bc / C_N;
    const int t    = threadIdx.x;
    const int lane = t & 63;
    const int wv   = t >> 6;

    for (int i = t; i < NBINS; i += SNT) hist[i] = 0;
    if (t == 0) { s_acc = 0; s_kout = 0; }
    __syncthreads();

    const float4* sptr = (const float4*)(scoresT + (size_t)bc * A_N);
    const float4* bptr = boxes + (size_t)b * A_N;
    float* optr = out + (size_t)bc * TOPK * 5;

    for (int i = 0; i < A_N / 4 / SNT; ++i) {
        float4 s4 = sptr[t + SNT * i];
        float s[4] = {s4.x, s4.y, s4.z, s4.w};
#pragma unroll
        for (int q = 0; q < 4; ++q) {
            if (s[q] > 0.3f) {
                unsigned u = __float_as_uint(s[q]);
                int bin = (int)(u >> 16) - (int)BIN_BASE;
                bin = bin < 0 ? 0 : (bin > NBINS - 1 ? NBINS - 1 : bin);
                atomicAdd(&hist[bin], 1);
            }
        }
    }
    __syncthreads();

    float rx1 = 0.f, ry1 = 0.f, rx2 = 0.f, ry2 = 0.f, rar = 0.f;
    int acc = 0, kout = 0;

    int bin_hi = NBINS;
    for (;;) {
        int lo = bin_hi, tot = 0;
        while (lo > 0) {
            int cnt = hist[lo - 1];
            if (tot + cnt > CAP) { if (tot == 0) { lo--; } break; }
            tot += cnt; lo--;
        }
        const int bin_lo = lo;
        if (bin_lo == bin_hi) break;
        if (t == 0) s_cnt = 0;
        __syncthreads();

        for (int i = 0; i < A_N / 4 / SNT; ++i) {
            float4 s4 = sptr[t + SNT * i];
            float s[4] = {s4.x, s4.y, s4.z, s4.w};
#pragma unroll
            for (int q = 0; q < 4; ++q) {
                if (s[q] > 0.3f) {
                    unsigned u = __float_as_uint(s[q]);
                    int bin = (int)(u >> 16) - (int)BIN_BASE;
                    bin = bin < 0 ? 0 : (bin > NBINS - 1 ? NBINS - 1 : bin);
                    if (bin >= bin_lo && bin < bin_hi) {
                        int slot = atomicAdd(&s_cnt, 1);
                        if (slot < CAP) {
                            unsigned a = (unsigned)(4 * (t + SNT * i) + q);
                            cand[slot] = ((unsigned long long)u << 32) | (unsigned)(~a);
                        }
                    }
                }
            }
        }
        __syncthreads();
        int C = s_cnt; if (C > CAP) C = CAP;

        if (C > 0) {
            if (wv == 0) {
                unsigned long long key[8];
#pragma unroll
                for (int r = 0; r < 8; ++r) {
                    int sidx = r * 64 + lane;
                    key[r] = (sidx < C) ? cand[sidx] : 0ull;
                }
#pragma unroll
                for (int k = 2; k <= CAP; k <<= 1) {
#pragma unroll
                    for (int j = k >> 1; j > 0; j >>= 1) {
                        if (j >= 64) {
                            int jr = j >> 6;
#pragma unroll
                            for (int r = 0; r < 8; ++r) {
                                int rp = r ^ jr;
                                if (rp > r) {
                                    int e = r * 64 + lane;
                                    bool up = ((e & k) == 0);
                                    unsigned long long va = key[r], vb = key[rp];
                                    bool sw = up ? (va < vb) : (va > vb);
                                    if (sw) { key[r] = vb; key[rp] = va; }
                                }
                            }
                        } else {
#pragma unroll
                            for (int r = 0; r < 8; ++r) {
                                int e = r * 64 + lane;
                                bool up    = ((e & k) == 0);
                                bool isLow = ((lane & j) == 0);
                                unsigned long long va = key[r];
                                unsigned long long vb = __shfl_xor(va, j, 64);
                                bool keepMax = (up == isLow);
                                key[r] = keepMax ? (va > vb ? va : vb)
                                                 : (va < vb ? va : vb);
                            }
                        }
                    }
                }
#pragma unroll
                for (int r = 0; r < 8; ++r) cand[r * 64 + lane] = key[r];
            }
            __syncthreads();

            for (int e = t; e < CAP; e += SNT)
                if (e < C) cbox[e] = bptr[(int)(~(unsigned)cand[e])];
            __syncthreads();

            if (wv == 0) {
                int ts = 0;
                unsigned long long k0 = cand[0];
                float4 cb = cbox[0];
                while (ts < C) {
                    unsigned long long nk = 0ull;
                    float4 nb = cb;
                    if (ts + 1 < C) { nk = cand[ts + 1]; nb = cbox[ts + 1]; }
                    float sc = __uint_as_float((unsigned)(k0 >> 32));
                    float ca = (cb.z - cb.x) * (cb.w - cb.y);
                    bool over = false;
                    if (lane < acc) {
                        float tlx = fmaxf(rx1, cb.x);
                        float tly = fmaxf(ry1, cb.y);
                        float brx = fminf(rx2, cb.z);
                        float bry = fminf(ry2, cb.w);
                        float iw  = fmaxf(brx - tlx, 0.0f);
                        float ih  = fmaxf(bry - tly, 0.0f);
                        float inter = iw * ih;
                        float iou = inter / (rar + ca - inter);
                        over = iou > 0.5f;
                    }
                    if (!__any(over)) {
                        if (lane == acc) { rx1 = cb.x; ry1 = cb.y; rx2 = cb.z; ry2 = cb.w; rar = ca; }
                        if (lane == 0) {
                            float* o = optr + (size_t)kout * 5;
                            o[0] = sc; o[1] = cb.x; o[2] = cb.y; o[3] = cb.z; o[4] = cb.w;
                        }
                        acc++; kout++;
                        if (acc == TOPK) break;
                    }
                    ++ts; k0 = nk; cb = nb;
                }
                if (lane == 0) { s_acc = acc; s_kout = kout; }
            }
            __syncthreads();
            if (s_acc >= TOPK) break;
        }
        bin_hi = bin_lo;
    }

    {
        const int ko = s_kout;
        float* o  = optr + (size_t)ko * 5;
        int   rem = (TOPK - ko) * 5;
        for (int i = t; i < rem; i += SNT) o[i] = 0.0f;
    }
}

// ---------------------------------------------------------------------------
// Tier-3 fallback: standalone one-wave NMS reading strided conf (r6-8 path).
// ---------------------------------------------------------------------------
__global__ __launch_bounds__(64, 4) void nms_fallback(const float* __restrict__ conf,
                                                      const float4* __restrict__ boxes,
                                                      float* __restrict__ out) {
    __shared__ int hist[NBINS];
    __shared__ unsigned long long cand[CAP];
    __shared__ float4 cbox[CAP];
    __shared__ int s_cnt;

    const int c    = blockIdx.x;
    const int b    = blockIdx.y;
    const int lane = threadIdx.x;

    const float4* bptr = boxes + (size_t)b * A_N;
    const float*  cptr = conf + (size_t)b * A_N * C_N + c;
    float* optr = out + (size_t)(b * C_N + c) * TOPK * 5;

    for (int i = lane; i < NBINS; i += 64) hist[i] = 0;
    __syncthreads();
    for (int i = 0; i < A_N / 256; ++i) {
        int a0 = 4 * (lane + 64 * i);
#pragma unroll
        for (int q = 0; q < 4; ++q) {
            float x = cptr[(size_t)(a0 + q) * C_N];
            float s = 1.0f / (1.0f + expf(-x));
            if (s > 0.3f) {
                unsigned u = __float_as_uint(s);
                int bin = (int)(u >> 16) - (int)BIN_BASE;
                bin = bin < 0 ? 0 : (bin > NBINS - 1 ? NBINS - 1 : bin);
                atomicAdd(&hist[bin], 1);
            }
        }
    }
    __syncthreads();

    float rx1 = 0.f, ry1 = 0.f, rx2 = 0.f, ry2 = 0.f, rar = 0.f;
    int acc = 0, kout = 0;
    int bin_hi = NBINS;
    for (;;) {
        int lo = bin_hi, tot = 0;
        while (lo > 0) {
            int cnt = hist[lo - 1];
            if (tot + cnt > CAP) { if (tot == 0) { lo--; } break; }
            tot += cnt; lo--;
        }
        const int bin_lo = lo;
        if (bin_lo == bin_hi) break;
        if (lane == 0) s_cnt = 0;
        __syncthreads();
        for (int i = 0; i < A_N / 256; ++i) {
            int a0 = 4 * (lane + 64 * i);
#pragma unroll
            for (int q = 0; q < 4; ++q) {
                float x = cptr[(size_t)(a0 + q) * C_N];
                float s = 1.0f / (1.0f + expf(-x));
                if (s > 0.3f) {
                    unsigned u = __float_as_uint(s);
                    int bin = (int)(u >> 16) - (int)BIN_BASE;
                    bin = bin < 0 ? 0 : (bin > NBINS - 1 ? NBINS - 1 : bin);
                    if (bin >= bin_lo && bin < bin_hi) {
                        int slot = atomicAdd(&s_cnt, 1);
                        if (slot < CAP)
                            cand[slot] = ((unsigned long long)u << 32) | (unsigned)(~(unsigned)(a0 + q));
                    }
                }
            }
        }
        __syncthreads();
        int C = s_cnt; if (C > CAP) C = CAP;
        if (C > 0)
            sort_gather_scan64(cand, cbox, C, lane, bptr, optr,
                               rx1, ry1, rx2, ry2, rar, acc, kout);
        if (acc == TOPK) break;
        bin_hi = bin_lo;
    }
    {
        float* o  = optr + (size_t)kout * 5;
        int   rem = (TOPK - kout) * 5;
        for (int i = lane; i < rem; i += 64) o[i] = 0.0f;
    }
}

extern "C" void kernel_launch(void* const* d_in, const int* in_sizes, int n_in,
                              void* d_out, int out_size, void* d_ws, size_t ws_size,
                              hipStream_t stream) {
    const float* loc     = (const float*)d_in[0];   // [B, A, 4]
    const float* conf    = (const float*)d_in[1];   // [B, A, C]
    const float* anchors = (const float*)d_in[2];   // [A, 4]
    float* out = (float*)d_out;                     // [B, C, TOPK, 5]

    const size_t boxes_bytes  = (size_t)B_N * A_N * sizeof(float4);          // 4 MB
    const size_t scores_bytes = (size_t)B_N * C_N * A_N * sizeof(float);     // 85 MB
    const size_t hist_bytes   = (size_t)BC_N * NBINS * sizeof(int);          // 1.2 MB
    const size_t fixed_bytes  = boxes_bytes + scores_bytes + hist_bytes;     // ~90.3 MB
    const size_t min_cand     = (size_t)BC_N * CAP * sizeof(unsigned long long); // 5.3 MB

    float4* boxes = (float4*)d_ws;

    decode_kernel<<<(B_N * A_N) / DNT, DNT, 0, stream>>>(
        (const float4*)loc, (const float4*)anchors, boxes);

    if (ws_size >= fixed_bytes + min_cand) {
        // gcap sized from available workspace (>=512 guaranteed by the check;
        // r2-r4 proved ws >= 95.65 MB so this path is the one that runs).
        size_t avail = ws_size - fixed_bytes;
        int gcap = (int)(avail / ((size_t)BC_N * sizeof(unsigned long long)));
        if (gcap > GCAP_MAX) gcap = GCAP_MAX;

        char* p = (char*)d_ws + boxes_bytes;
        float* scoresT = (float*)p;                 p += scores_bytes;
        int* g_hist = (int*)p;                      p += hist_bytes;
        unsigned long long* g_cand = (unsigned long long*)p;

        sigT_kernel<<<dim3(A_N / TA, B_N), TNT, 0, stream>>>(conf, scoresT);
        select_kernel<<<dim3(BC_N), SNT, 0, stream>>>(scoresT, g_cand, g_hist, gcap);
        nms_banded_kernel<<<dim3(BC_N), 64, 0, stream>>>(scoresT, boxes, g_cand,
                                                         g_hist, out, gcap);
    } else if (ws_size >= boxes_bytes + scores_bytes) {
        float* scoresT = (float*)((char*)d_ws + boxes_bytes);
        sigT_kernel<<<dim3(A_N / TA, B_N), TNT, 0, stream>>>(conf, scoresT);
        select_nms_fused<<<dim3(BC_N), SNT, 0, stream>>>(scoresT, boxes, out);
    } else {
        nms_fallback<<<dim3(C_N, B_N), 64, 0, stream>>>(conf, boxes, out);
    }
}